// Round 1
// baseline (140.820 us; speedup 1.0000x reference)
//
#include <hip/hip_runtime.h>
#include <hip/hip_bf16.h>

typedef float f32x4 __attribute__((ext_vector_type(4)));
typedef __bf16 bf16x8 __attribute__((ext_vector_type(8)));

static constexpr int BB = 32;      // batch
static constexpr int DM = 2560;    // d_model
static constexpr int DI = 5120;    // d_inner
static constexpr int NS = 16;      // ssm state N
static constexpr int RK = 160;     // dt_rank
static constexpr int NJ = 192;     // dt_rank + 2N

__device__ __forceinline__ float sigmoidf_(float x) { return 1.f / (1.f + __expf(-x)); }
__device__ __forceinline__ float softplusf_(float x) {
    return (x > 15.f) ? x : log1pf(__expf(x));
}

// ---------------------------------------------------------------------------
// Generic skinny GEMM: C[b][d] += sum_k W[d][k] * X[b][k], b = 0..31.
// Block = 256 thr = 4 waves; per block: 32 d-rows x 32 batch, BK=64 per step.
// Split-K + dual-matrix select via blockIdx. Epilogue: atomicAdd (C pre-zeroed).
// LDS rows padded to 72 bf16 (144 B = 9 x 16 B) -> bank-quad rotation, no XOR.
// ---------------------------------------------------------------------------
__global__ __launch_bounds__(256) void gemm32(
    const float* __restrict__ W0, float* __restrict__ C0,
    const float* __restrict__ W1, float* __restrict__ C1,
    const float* __restrict__ X,
    int K, int ldc, int nm, int S, int ksteps)
{
    __shared__ __bf16 Wt[32][72];
    __shared__ __bf16 Xt[32][72];

    int bid = blockIdx.x;
    int m = bid % nm;
    int rest = bid / nm;
    int s = rest % S;
    int mat = rest / S;
    const float* W = mat ? W1 : W0;
    float* C = mat ? C1 : C0;

    int d0 = m * 32;
    int k0 = s * (K / S);

    int t = threadIdx.x;
    int srow = t >> 3;          // 0..31 staging row
    int sch  = t & 7;           // 0..7 16B chunk within row (8 bf16)

    const float* wp = W + (size_t)(d0 + srow) * K + k0 + sch * 8;
    const float* xp = X + (size_t)srow * K + k0 + sch * 8;

    int l  = t & 63;
    int wv = t >> 6;            // wave 0..3
    int mh = wv & 1;            // m-half of 32x32 tile
    int nh = wv >> 1;           // n-half
    int arow = mh * 16 + (l & 15);
    int brow = nh * 16 + (l & 15);
    int cb   = l >> 4;          // k-chunk base within frag

    f32x4 acc = {0.f, 0.f, 0.f, 0.f};

    for (int it = 0; it < ksteps; ++it) {
        float4 wa = *(const float4*)wp;
        float4 wb = *(const float4*)(wp + 4);
        float4 xa = *(const float4*)xp;
        float4 xb = *(const float4*)(xp + 4);
        wp += 64; xp += 64;

        __syncthreads();   // previous iteration's frag reads done

        bf16x8 pw, px;
        pw[0] = (__bf16)wa.x; pw[1] = (__bf16)wa.y; pw[2] = (__bf16)wa.z; pw[3] = (__bf16)wa.w;
        pw[4] = (__bf16)wb.x; pw[5] = (__bf16)wb.y; pw[6] = (__bf16)wb.z; pw[7] = (__bf16)wb.w;
        px[0] = (__bf16)xa.x; px[1] = (__bf16)xa.y; px[2] = (__bf16)xa.z; px[3] = (__bf16)xa.w;
        px[4] = (__bf16)xb.x; px[5] = (__bf16)xb.y; px[6] = (__bf16)xb.z; px[7] = (__bf16)xb.w;
        *(bf16x8*)&Wt[srow][sch * 8] = pw;
        *(bf16x8*)&Xt[srow][sch * 8] = px;

        __syncthreads();

        bf16x8 a0 = *(const bf16x8*)&Wt[arow][cb * 8];
        bf16x8 b0 = *(const bf16x8*)&Xt[brow][cb * 8];
        acc = __builtin_amdgcn_mfma_f32_16x16x32_bf16(a0, b0, acc, 0, 0, 0);
        bf16x8 a1 = *(const bf16x8*)&Wt[arow][(cb + 4) * 8];
        bf16x8 b1 = *(const bf16x8*)&Xt[brow][(cb + 4) * 8];
        acc = __builtin_amdgcn_mfma_f32_16x16x32_bf16(a1, b1, acc, 0, 0, 0);
    }

    // C/D layout (m89-verified): col = lane&15 (batch), row = (lane>>4)*4 + j (d)
    int b = brow;
    int dbase = d0 + mh * 16 + (l >> 4) * 4;
    #pragma unroll
    for (int j = 0; j < 4; ++j)
        atomicAdd(&C[(size_t)b * ldc + dbase + j], acc[j]);
}

// ---------------------------------------------------------------------------
// Depthwise causal conv (k=4, shift register) + SiLU.
// conv[b,d] = silu(cs[1..3]*w[0..2] + xs*w[3] + bias)
// ---------------------------------------------------------------------------
__global__ __launch_bounds__(256) void convk(
    const float* __restrict__ xs_bd, const float* __restrict__ conv_states,
    const float* __restrict__ conv_w, const float* __restrict__ conv_b,
    float* __restrict__ conv_bd)
{
    int d = blockIdx.x * 256 + threadIdx.x;
    int b = blockIdx.y;
    size_t o = (size_t)b * DI + d;
    float v = conv_states[(size_t)(1 * BB + b) * DI + d] * conv_w[0 * DI + d]
            + conv_states[(size_t)(2 * BB + b) * DI + d] * conv_w[1 * DI + d]
            + conv_states[(size_t)(3 * BB + b) * DI + d] * conv_w[2 * DI + d]
            + xs_bd[o] * conv_w[3 * DI + d] + conv_b[d];
    conv_bd[o] = v * sigmoidf_(v);
}

// ---------------------------------------------------------------------------
// dt GEMV (K=160) + softplus + SSM recurrence + D skip + SiLU gate.
// Block: 256 thr = 32 d x 8 b-groups (4 b each). Grid: DI/32 = 160.
// W_dt tile + x_db^T staged in LDS (coalesced global reads).
// ---------------------------------------------------------------------------
__global__ __launch_bounds__(256) void ssmk(
    const float* __restrict__ x_db, const float* __restrict__ W_dt,
    const float* __restrict__ dt_bias, const float* __restrict__ A_log,
    const float* __restrict__ Dv, const float* __restrict__ ssm_state,
    const float* __restrict__ conv_bd, const float* __restrict__ res_bd,
    float* __restrict__ g_bd)
{
    __shared__ float Wdt[32][164];   // pad 164: 656 B rows, 16B aligned, quads spread
    __shared__ float xdbT[NJ][36];   // pad 36: 144 B rows

    int t = threadIdx.x;
    int d0 = blockIdx.x * 32;

    for (int f = t; f < 32 * RK; f += 256) {
        int r = f / RK, c = f % RK;
        Wdt[r][c] = W_dt[(size_t)d0 * RK + f];   // contiguous slab, coalesced
    }
    for (int f = t; f < BB * NJ; f += 256) {
        int b = f / NJ, j = f % NJ;
        xdbT[j][b] = x_db[f];
    }
    __syncthreads();

    int dl = t & 31;
    int bg = t >> 5;          // 0..7 -> b = bg*4 + i

    f32x4 acc = {0.f, 0.f, 0.f, 0.f};
    for (int r = 0; r < RK; r += 4) {
        f32x4 wv4 = *(const f32x4*)&Wdt[dl][r];
        #pragma unroll
        for (int rr = 0; rr < 4; ++rr) {
            f32x4 xv = *(const f32x4*)&xdbT[r + rr][bg * 4];
            acc[0] += wv4[rr] * xv[0];
            acc[1] += wv4[rr] * xv[1];
            acc[2] += wv4[rr] * xv[2];
            acc[3] += wv4[rr] * xv[3];
        }
    }

    float dtb = dt_bias[d0 + dl];
    float dtv[4];
    #pragma unroll
    for (int i = 0; i < 4; ++i) dtv[i] = softplusf_(acc[i] + dtb);

    float Dd = Dv[d0 + dl];
    float Av[16];
    #pragma unroll
    for (int n = 0; n < NS; ++n)
        Av[n] = -__expf(A_log[(size_t)(d0 + dl) * NS + n]);

    #pragma unroll
    for (int i = 0; i < 4; ++i) {
        int b = bg * 4 + i;
        size_t off = (size_t)b * DI + d0 + dl;
        float cv = conv_bd[off];
        float rv = res_bd[off];
        const f32x4* sp = (const f32x4*)(ssm_state + off * NS);
        float dti = dtv[i];
        float yy = 0.f;
        #pragma unroll
        for (int n4 = 0; n4 < 4; ++n4) {
            f32x4 sv = sp[n4];
            #pragma unroll
            for (int nn = 0; nn < 4; ++nn) {
                int n = n4 * 4 + nn;
                float Bn = xdbT[RK + n][b];
                float Cn = xdbT[RK + NS + n][b];
                yy += (sv[nn] * __expf(dti * Av[n]) + dti * Bn * cv) * Cn;
            }
        }
        yy += Dd * cv;
        g_bd[off] = yy * (rv * sigmoidf_(rv));
    }
}

// ---------------------------------------------------------------------------

extern "C" void kernel_launch(void* const* d_in, const int* in_sizes, int n_in,
                              void* d_out, int out_size, void* d_ws, size_t ws_size,
                              hipStream_t stream)
{
    const float* x           = (const float*)d_in[0];
    const float* conv_states = (const float*)d_in[1];
    const float* conv_w      = (const float*)d_in[2];
    const float* conv_b      = (const float*)d_in[3];
    const float* W_ssm_in    = (const float*)d_in[4];
    const float* W_mlp       = (const float*)d_in[5];
    const float* W_out       = (const float*)d_in[6];
    const float* W_x_proj    = (const float*)d_in[7];
    const float* W_dt        = (const float*)d_in[8];
    const float* dt_bias     = (const float*)d_in[9];
    const float* A_log       = (const float*)d_in[10];
    const float* Dv          = (const float*)d_in[11];
    const float* ssm_state   = (const float*)d_in[12];

    float* out = (float*)d_out;
    float* ws  = (float*)d_ws;

    const size_t BD = (size_t)BB * DI;         // 163840
    float* res_bd  = ws;
    float* xs_bd   = ws + BD;
    float* conv_bd = ws + 2 * BD;
    float* x_db    = ws + 3 * BD;              // 32*192 = 6144
    float* g_bd    = ws + 3 * BD + BB * NJ;

    // zero the atomically-accumulated buffers (res, xs, x_db) + d_out
    hipMemsetAsync(ws, 0, (3 * BD + BB * NJ) * sizeof(float), stream);
    hipMemsetAsync(d_out, 0, (size_t)out_size * sizeof(float), stream);

    // K1: res = x @ W_mlp.T ; xs = x @ W_ssm_in.T   (K=2560, split-K 4, dual)
    gemm32<<<dim3(160 * 4 * 2), 256, 0, stream>>>(
        W_mlp, res_bd, W_ssm_in, xs_bd, x, DM, DI, 160, 4, (DM / 4) / 64);

    // K1.5: depthwise conv + silu
    convk<<<dim3(DI / 256, BB), 256, 0, stream>>>(xs_bd, conv_states, conv_w, conv_b, conv_bd);

    // K2: x_db = conv @ W_x_proj.T   (D=192, K=5120, split-K 40)
    gemm32<<<dim3(6 * 40), 256, 0, stream>>>(
        W_x_proj, x_db, W_x_proj, x_db, conv_bd, DI, NJ, 6, 40, (DI / 40) / 64);

    // K3: dt + SSM + gate -> g
    ssmk<<<dim3(DI / 32), 256, 0, stream>>>(
        x_db, W_dt, dt_bias, A_log, Dv, ssm_state, conv_bd, res_bd, g_bd);

    // K4: out = g @ W_out.T   (D=2560, K=5120, split-K 16)
    gemm32<<<dim3(80 * 16), 256, 0, stream>>>(
        W_out, out, W_out, out, g_bd, DI, DM, 80, 16, (DI / 16) / 64);
}

// Round 2
// 88.613 us; speedup vs baseline: 1.5892x; 1.5892x over previous
//
#include <hip/hip_runtime.h>
#include <hip/hip_bf16.h>

typedef float f32x4 __attribute__((ext_vector_type(4)));
typedef __bf16 bf16x8 __attribute__((ext_vector_type(8)));

static constexpr int BB = 32;      // batch
static constexpr int DM = 2560;    // d_model
static constexpr int DI = 5120;    // d_inner
static constexpr int NS = 16;      // ssm state N
static constexpr int RK = 160;     // dt_rank
static constexpr int NJ = 192;     // dt_rank + 2N

__device__ __forceinline__ float sigmoidf_(float x) { return 1.f / (1.f + __expf(-x)); }
__device__ __forceinline__ float softplusf_(float x) {
    return (x > 15.f) ? x : log1pf(__expf(x));
}

// ---------------------------------------------------------------------------
// Generic skinny GEMM: C[b][d] += sum_k W[d][k] * X[b][k], b = 0..31.
// Block = 256 thr = 4 waves; per block: 32 d-rows x 32 batch, BK=64 per step.
// Split-K + dual-matrix select via blockIdx. Epilogue: atomicAdd (C pre-zeroed).
// ---------------------------------------------------------------------------
__global__ __launch_bounds__(256) void gemm32(
    const float* __restrict__ W0, float* __restrict__ C0,
    const float* __restrict__ W1, float* __restrict__ C1,
    const float* __restrict__ X,
    int K, int ldc, int nm, int S, int ksteps)
{
    __shared__ __bf16 Wt[32][72];
    __shared__ __bf16 Xt[32][72];

    int bid = blockIdx.x;
    int m = bid % nm;
    int rest = bid / nm;
    int s = rest % S;
    int mat = rest / S;
    const float* W = mat ? W1 : W0;
    float* C = mat ? C1 : C0;

    int d0 = m * 32;
    int k0 = s * (K / S);

    int t = threadIdx.x;
    int srow = t >> 3;          // 0..31 staging row
    int sch  = t & 7;           // 0..7 16B chunk within row (8 bf16)

    const float* wp = W + (size_t)(d0 + srow) * K + k0 + sch * 8;
    const float* xp = X + (size_t)srow * K + k0 + sch * 8;

    int l  = t & 63;
    int wv = t >> 6;            // wave 0..3
    int mh = wv & 1;            // m-half of 32x32 tile
    int nh = wv >> 1;           // n-half
    int arow = mh * 16 + (l & 15);
    int brow = nh * 16 + (l & 15);
    int cb   = l >> 4;          // k-chunk base within frag

    f32x4 acc = {0.f, 0.f, 0.f, 0.f};

    for (int it = 0; it < ksteps; ++it) {
        float4 wa = *(const float4*)wp;
        float4 wb = *(const float4*)(wp + 4);
        float4 xa = *(const float4*)xp;
        float4 xb = *(const float4*)(xp + 4);
        wp += 64; xp += 64;

        __syncthreads();   // previous iteration's frag reads done

        bf16x8 pw, px;
        pw[0] = (__bf16)wa.x; pw[1] = (__bf16)wa.y; pw[2] = (__bf16)wa.z; pw[3] = (__bf16)wa.w;
        pw[4] = (__bf16)wb.x; pw[5] = (__bf16)wb.y; pw[6] = (__bf16)wb.z; pw[7] = (__bf16)wb.w;
        px[0] = (__bf16)xa.x; px[1] = (__bf16)xa.y; px[2] = (__bf16)xa.z; px[3] = (__bf16)xa.w;
        px[4] = (__bf16)xb.x; px[5] = (__bf16)xb.y; px[6] = (__bf16)xb.z; px[7] = (__bf16)xb.w;
        *(bf16x8*)&Wt[srow][sch * 8] = pw;
        *(bf16x8*)&Xt[srow][sch * 8] = px;

        __syncthreads();

        bf16x8 a0 = *(const bf16x8*)&Wt[arow][cb * 8];
        bf16x8 b0 = *(const bf16x8*)&Xt[brow][cb * 8];
        acc = __builtin_amdgcn_mfma_f32_16x16x32_bf16(a0, b0, acc, 0, 0, 0);
        bf16x8 a1 = *(const bf16x8*)&Wt[arow][(cb + 4) * 8];
        bf16x8 b1 = *(const bf16x8*)&Xt[brow][(cb + 4) * 8];
        acc = __builtin_amdgcn_mfma_f32_16x16x32_bf16(a1, b1, acc, 0, 0, 0);
    }

    // C/D layout (m89-verified): col = lane&15 (batch), row = (lane>>4)*4 + j (d)
    int b = brow;
    int dbase = d0 + mh * 16 + (l >> 4) * 4;
    #pragma unroll
    for (int j = 0; j < 4; ++j)
        atomicAdd(&C[(size_t)b * ldc + dbase + j], acc[j]);
}

// ---------------------------------------------------------------------------
// Depthwise causal conv (k=4, shift register) + SiLU.
// ---------------------------------------------------------------------------
__global__ __launch_bounds__(256) void convk(
    const float* __restrict__ xs_bd, const float* __restrict__ conv_states,
    const float* __restrict__ conv_w, const float* __restrict__ conv_b,
    float* __restrict__ conv_bd)
{
    int d = blockIdx.x * 256 + threadIdx.x;
    int b = blockIdx.y;
    size_t o = (size_t)b * DI + d;
    float v = conv_states[(size_t)(1 * BB + b) * DI + d] * conv_w[0 * DI + d]
            + conv_states[(size_t)(2 * BB + b) * DI + d] * conv_w[1 * DI + d]
            + conv_states[(size_t)(3 * BB + b) * DI + d] * conv_w[2 * DI + d]
            + xs_bd[o] * conv_w[3 * DI + d] + conv_b[d];
    conv_bd[o] = v * sigmoidf_(v);
}

// ---------------------------------------------------------------------------
// dt GEMV: dt[b][d] = softplus(x_db[b,0:160] @ W_dt[d,:] + dt_bias[d]).
// Block = 256 thr = 8 d x 32 b.  Grid = DI/8 = 640 blocks.
// Both operands LDS-staged; W_dt read coalesced once per block.
// ---------------------------------------------------------------------------
__global__ __launch_bounds__(256) void dtk(
    const float* __restrict__ x_db, const float* __restrict__ W_dt,
    const float* __restrict__ dt_bias, float* __restrict__ dt_bd)
{
    __shared__ float Wdt_s[8][164];
    __shared__ float xdb_s[BB][164];

    int t = threadIdx.x;
    int d0 = blockIdx.x * 8;

    for (int f = t; f < 8 * RK; f += 256) {
        Wdt_s[f / RK][f % RK] = W_dt[(size_t)d0 * RK + f];
    }
    for (int f = t; f < BB * RK; f += 256) {
        int b = f / RK, k = f % RK;
        xdb_s[b][k] = x_db[(size_t)b * NJ + k];
    }
    __syncthreads();

    int b  = t & 31;
    int dl = t >> 5;            // 0..7

    float acc = 0.f;
    #pragma unroll 8
    for (int k4 = 0; k4 < RK / 4; ++k4) {
        f32x4 wv = *(const f32x4*)&Wdt_s[dl][k4 * 4];
        f32x4 xv = *(const f32x4*)&xdb_s[b][k4 * 4];
        acc += wv[0] * xv[0] + wv[1] * xv[1] + wv[2] * xv[2] + wv[3] * xv[3];
    }

    int d = d0 + dl;
    dt_bd[(size_t)b * DI + d] = softplusf_(acc + dt_bias[d]);
}

// ---------------------------------------------------------------------------
// SSM recurrence + D skip + SiLU gate.  One thread per (b,d).
// Grid: b-major: blockIdx.x = b*20 + dblk.  All coalesced 64B/thread reads.
// ---------------------------------------------------------------------------
__global__ __launch_bounds__(256) void ssm2(
    const float* __restrict__ x_db, const float* __restrict__ dt_bd,
    const float* __restrict__ A_log, const float* __restrict__ Dv,
    const float* __restrict__ ssm_state, const float* __restrict__ conv_bd,
    const float* __restrict__ res_bd, float* __restrict__ g_bd)
{
    __shared__ float Bc[NS], Cc[NS];

    int t = threadIdx.x;
    int b = blockIdx.x / (DI / 256);
    int dblk = blockIdx.x % (DI / 256);
    int d = dblk * 256 + t;

    if (t < NS) Bc[t] = x_db[(size_t)b * NJ + RK + t];
    else if (t < 2 * NS) Cc[t - NS] = x_db[(size_t)b * NJ + RK + t - NS + NS];
    __syncthreads();

    size_t off = (size_t)b * DI + d;
    float dt = dt_bd[off];
    float cv = conv_bd[off];
    float rv = res_bd[off];
    float Dd = Dv[d];

    const f32x4* ap = (const f32x4*)(A_log + (size_t)d * NS);
    const f32x4* sp = (const f32x4*)(ssm_state + off * NS);

    float y = 0.f;
    #pragma unroll
    for (int q = 0; q < 4; ++q) {
        f32x4 al = ap[q];
        f32x4 sv = sp[q];
        #pragma unroll
        for (int j = 0; j < 4; ++j) {
            int n = q * 4 + j;
            float dA = __expf(-dt * __expf(al[j]));   // exp(dt * (-exp(A_log)))
            y += (sv[j] * dA + dt * Bc[n] * cv) * Cc[n];
        }
    }
    y += Dd * cv;
    g_bd[off] = y * (rv * sigmoidf_(rv));
}

// ---------------------------------------------------------------------------

extern "C" void kernel_launch(void* const* d_in, const int* in_sizes, int n_in,
                              void* d_out, int out_size, void* d_ws, size_t ws_size,
                              hipStream_t stream)
{
    const float* x           = (const float*)d_in[0];
    const float* conv_states = (const float*)d_in[1];
    const float* conv_w      = (const float*)d_in[2];
    const float* conv_b      = (const float*)d_in[3];
    const float* W_ssm_in    = (const float*)d_in[4];
    const float* W_mlp       = (const float*)d_in[5];
    const float* W_out       = (const float*)d_in[6];
    const float* W_x_proj    = (const float*)d_in[7];
    const float* W_dt        = (const float*)d_in[8];
    const float* dt_bias     = (const float*)d_in[9];
    const float* A_log       = (const float*)d_in[10];
    const float* Dv          = (const float*)d_in[11];
    const float* ssm_state   = (const float*)d_in[12];

    float* out = (float*)d_out;
    float* ws  = (float*)d_ws;

    const size_t BD = (size_t)BB * DI;         // 163840
    float* res_bd  = ws;
    float* xs_bd   = ws + BD;
    float* conv_bd = ws + 2 * BD;
    float* x_db    = ws + 3 * BD;              // 32*192 = 6144
    float* g_bd    = ws + 3 * BD + BB * NJ;
    float* dt_bd   = ws + 4 * BD + BB * NJ;

    // zero the atomically-accumulated buffers (res, xs, x_db) + d_out
    hipMemsetAsync(ws, 0, (3 * BD + BB * NJ) * sizeof(float), stream);
    hipMemsetAsync(d_out, 0, (size_t)out_size * sizeof(float), stream);

    // K1: res = x @ W_mlp.T ; xs = x @ W_ssm_in.T   (K=2560, split-K 4, dual)
    gemm32<<<dim3(160 * 4 * 2), 256, 0, stream>>>(
        W_mlp, res_bd, W_ssm_in, xs_bd, x, DM, DI, 160, 4, (DM / 4) / 64);

    // K1.5: depthwise conv + silu
    convk<<<dim3(DI / 256, BB), 256, 0, stream>>>(xs_bd, conv_states, conv_w, conv_b, conv_bd);

    // K2: x_db = conv @ W_x_proj.T   (D=192, K=5120, split-K 40)
    gemm32<<<dim3(6 * 40), 256, 0, stream>>>(
        W_x_proj, x_db, W_x_proj, x_db, conv_bd, DI, NJ, 6, 40, (DI / 40) / 64);

    // K3a: dt GEMV + softplus
    dtk<<<dim3(DI / 8), 256, 0, stream>>>(x_db, W_dt, dt_bias, dt_bd);

    // K3b: SSM recurrence + gate
    ssm2<<<dim3(BB * (DI / 256)), 256, 0, stream>>>(
        x_db, dt_bd, A_log, Dv, ssm_state, conv_bd, res_bd, g_bd);

    // K4: out = g @ W_out.T   (D=2560, K=5120, split-K 16)
    gemm32<<<dim3(80 * 16), 256, 0, stream>>>(
        W_out, out, W_out, out, g_bd, DI, DM, 80, 16, (DI / 16) / 64);
}